// Round 4
// baseline (2070.448 us; speedup 1.0000x reference)
//
#include <hip/hip_runtime.h>
#include <hip/hip_bf16.h>

#define TT 1024
#define BB 512

typedef _Float16 half_t;
typedef __attribute__((ext_vector_type(8))) _Float16 v8h;
typedef __attribute__((ext_vector_type(4))) float v4f;

__device__ __forceinline__ float sigf(float x) { return 1.0f / (1.0f + __expf(-x)); }
__device__ __forceinline__ float tanhfast(float x) { return 2.0f / (1.0f + __expf(-2.0f * x)) - 1.0f; }

// Drain ONLY lgkmcnt (LDS) at the barrier — global prefetch stays in flight.
__device__ __forceinline__ void barrier_lds_only() {
    asm volatile("s_waitcnt lgkmcnt(0)\n\ts_barrier" ::: "memory");
}

// LSTM scan. Batch row r of the block is mapped to MFMA A/C row 4r, so the
// cell state for row r lives on lane group q==r, C-reg 0: the nonlinearity
// executes ONCE (not R times) across lane groups in parallel.
// 256 threads = 4 waves; wave wv owns gate columns {gt*64 + wv*16 + n16}.
// h double-buffered in LDS (rows padded to 72 halfs: b128 bank groups spread
// (n16+q)%8 -> minimum-clock access). One lds-only barrier per step.
template<int R, bool IN_F32, bool W16, bool WRITE_SEQ, bool WRITE_LAST>
__global__ __launch_bounds__(256, 2)
void lstm_scan(const void* __restrict__ in_v, const half_t* __restrict__ w16,
               const float* __restrict__ w_ih, const float* __restrict__ w_hh,
               const float* __restrict__ b_ih, const float* __restrict__ b_hh,
               int layer, int use_grid_dir,
               half_t* __restrict__ out_seq, float* __restrict__ out_last)
{
    const int dir = use_grid_dir ? blockIdx.y : 0;
    const int wrow = layer * 2 + dir;
    const int col_off = dir * 64;
    const int b0 = blockIdx.x * R;
    const int wv = threadIdx.x >> 6;
    const int l  = threadIdx.x & 63;
    const int q  = l >> 4;
    const int n16 = l & 15;
    const int j = wv * 16 + n16;
    // A-row n16 carries batch row n16>>2 (clamped) -- only rows 4r are consumed.
    const int rowc = ((n16 >> 2) < R) ? (n16 >> 2) : (R - 1);

    __shared__ __align__(16) half_t hs[2][16][72];  // 4608 B
    {
        v8h z;
        #pragma unroll
        for (int e = 0; e < 8; ++e) z[e] = (half_t)0.f;
        ((v8h*)hs)[threadIdx.x] = z;
        if (threadIdx.x < 32) ((v8h*)hs)[256 + threadIdx.x] = z;
    }

    // ---- weight B-fragments: B[k][n16] = W[gt*64+j][k], k = kt*32+q*8+e ----
    v8h wb[4][6];
    float bias[4];
    #pragma unroll
    for (int gt = 0; gt < 4; ++gt) {
        const int grow = wrow * 256 + gt * 64 + j;
        if constexpr (W16) {
            const half_t* p = w16 + (size_t)grow * 192 + q * 8;
            #pragma unroll
            for (int kt = 0; kt < 6; ++kt) wb[gt][kt] = *(const v8h*)(p + kt * 32);
        } else {
            const float* pih = w_ih + (size_t)grow * 128 + q * 8;
            #pragma unroll
            for (int kt = 0; kt < 4; ++kt) {
                const float4 a = *(const float4*)(pih + kt * 32);
                const float4 b = *(const float4*)(pih + kt * 32 + 4);
                v8h f;
                f[0] = (half_t)a.x; f[1] = (half_t)a.y; f[2] = (half_t)a.z; f[3] = (half_t)a.w;
                f[4] = (half_t)b.x; f[5] = (half_t)b.y; f[6] = (half_t)b.z; f[7] = (half_t)b.w;
                wb[gt][kt] = f;
            }
            const float* phh = w_hh + (size_t)grow * 64 + q * 8;
            #pragma unroll
            for (int kt = 0; kt < 2; ++kt) {
                const float4 a = *(const float4*)(phh + kt * 32);
                const float4 b = *(const float4*)(phh + kt * 32 + 4);
                v8h f;
                f[0] = (half_t)a.x; f[1] = (half_t)a.y; f[2] = (half_t)a.z; f[3] = (half_t)a.w;
                f[4] = (half_t)b.x; f[5] = (half_t)b.y; f[6] = (half_t)b.z; f[7] = (half_t)b.w;
                wb[gt][4 + kt] = f;
            }
        }
        bias[gt] = b_ih[grow] + b_hh[grow];
    }

    const long t0 = dir ? (TT - 1) : 0;
    const long xstep = dir ? -128 : 128;

    const float*  xp32 = nullptr;
    const half_t* xp16 = nullptr;
    if constexpr (IN_F32) xp32 = (const float*)in_v + ((size_t)(b0 + rowc) * TT + t0) * 128 + q * 8;
    else                  xp16 = (const half_t*)in_v + ((size_t)(b0 + rowc) * TT + t0) * 128 + q * 8;

    half_t* op = nullptr;
    if constexpr (WRITE_SEQ) {
        const int qr = (q < R) ? q : (R - 1);
        op = out_seq + ((size_t)(b0 + qr) * TT + t0) * 128 + col_off + j;
    }

    auto load_x = [&](v8h* dst) {
        if constexpr (IN_F32) {
            #pragma unroll
            for (int kt = 0; kt < 4; ++kt) {
                const float4 a = *(const float4*)(xp32 + kt * 32);
                const float4 b = *(const float4*)(xp32 + kt * 32 + 4);
                v8h f;
                f[0] = (half_t)a.x; f[1] = (half_t)a.y; f[2] = (half_t)a.z; f[3] = (half_t)a.w;
                f[4] = (half_t)b.x; f[5] = (half_t)b.y; f[6] = (half_t)b.z; f[7] = (half_t)b.w;
                dst[kt] = f;
            }
        } else {
            #pragma unroll
            for (int kt = 0; kt < 4; ++kt) dst[kt] = *(const v8h*)(xp16 + kt * 32);
        }
    };
    auto adv_x = [&]() { if constexpr (IN_F32) xp32 += xstep; else xp16 += xstep; };

    float c = 0.f, hcur = 0.f;

    auto step = [&](const v8h* xf, int pb) {
        const v8h hf0 = *(const v8h*)&hs[pb][n16][q * 8];
        const v8h hf1 = *(const v8h*)&hs[pb][n16][32 + q * 8];
        const v4f z4 = {0.f, 0.f, 0.f, 0.f};
        v4f acc[4];
        #pragma unroll
        for (int gt = 0; gt < 4; ++gt) {
            v4f a = z4;
            a = __builtin_amdgcn_mfma_f32_16x16x32_f16(xf[0], wb[gt][0], a, 0, 0, 0);
            a = __builtin_amdgcn_mfma_f32_16x16x32_f16(xf[1], wb[gt][1], a, 0, 0, 0);
            a = __builtin_amdgcn_mfma_f32_16x16x32_f16(xf[2], wb[gt][2], a, 0, 0, 0);
            a = __builtin_amdgcn_mfma_f32_16x16x32_f16(xf[3], wb[gt][3], a, 0, 0, 0);
            a = __builtin_amdgcn_mfma_f32_16x16x32_f16(hf0,   wb[gt][4], a, 0, 0, 0);
            a = __builtin_amdgcn_mfma_f32_16x16x32_f16(hf1,   wb[gt][5], a, 0, 0, 0);
            acc[gt] = a;
        }
        // cell update: batch row q on lanes q<R, C-reg 0
        const float iv = sigf(acc[0][0] + bias[0]);
        const float fv = sigf(acc[1][0] + bias[1]);
        const float gv = tanhfast(acc[2][0] + bias[2]);
        const float ov = sigf(acc[3][0] + bias[3]);
        c = fv * c + iv * gv;
        const float h = ov * tanhfast(c);
        if (q < R) {
            const half_t h16 = (half_t)h;
            hs[pb ^ 1][4 * q][j] = h16;
            if constexpr (WRITE_SEQ) { *op = h16; op += xstep; }
            hcur = h;
        }
    };

    v8h xA[4], xB[4];
    load_x(xA);
    adv_x();
    barrier_lds_only();  // hs zero-init visible

    for (int tt = 0; tt < TT; tt += 2) {
        if (tt + 1 < TT) load_x(xB);
        adv_x();
        step(xA, 0);          // read hs[0], write hs[1]
        barrier_lds_only();
        if (tt + 2 < TT) load_x(xA);
        adv_x();
        step(xB, 1);          // read hs[1], write hs[0]
        barrier_lds_only();
    }

    if constexpr (WRITE_LAST) {
        if (q < R) out_last[(size_t)(b0 + q) * 64 + j] = hcur;
    }
}

// ---------------- weight fp32 -> packed fp16 rows of 192 ----------------
__global__ __launch_bounds__(256)
void cvt_w(const float* __restrict__ w_ih, const float* __restrict__ w_hh,
           half_t* __restrict__ w16)
{
    const int id = blockIdx.x * 256 + threadIdx.x;  // 1024 rows * 192
    const int row = id / 192, k = id % 192;
    const float v = (k < 128) ? w_ih[row * 128 + k] : w_hh[row * 64 + (k - 128)];
    w16[id] = (half_t)v;
}

// ---------------- x fp32 -> fp16 ----------------
__global__ __launch_bounds__(256)
void cvt_x(const float* __restrict__ in, half_t* __restrict__ out)
{
    const size_t i = ((size_t)blockIdx.x * 256 + threadIdx.x) * 8;
    const float4 a = *(const float4*)(in + i);
    const float4 b = *(const float4*)(in + i + 4);
    v8h f;
    f[0] = (half_t)a.x; f[1] = (half_t)a.y; f[2] = (half_t)a.z; f[3] = (half_t)a.w;
    f[4] = (half_t)b.x; f[5] = (half_t)b.y; f[6] = (half_t)b.z; f[7] = (half_t)b.w;
    *(v8h*)(out + i) = f;
}

// ---------------- Layer 2 backward (single step, h0=0) + FC ----------------
__global__ __launch_bounds__(256)
void l2bwd_fc(const half_t* __restrict__ in, const float* __restrict__ w_ih,
              const float* __restrict__ b_ih, const float* __restrict__ b_hh,
              const float* __restrict__ hlast, const float* __restrict__ fc_w,
              const float* __restrict__ fc_b, float* __restrict__ out)
{
    const int b = blockIdx.x;
    const int g = threadIdx.x;
    __shared__ float gpre[256];
    __shared__ float hb[64];

    float acc = b_ih[3 * 256 + g] + b_hh[3 * 256 + g];
    const float* wp = w_ih + ((size_t)(3 * 256 + g)) * 128;
    const half_t* xp = in + ((size_t)b * TT + (TT - 1)) * 128;
    #pragma unroll
    for (int k = 0; k < 128; k += 8) {
        const float4 w0 = *(const float4*)(wp + k);
        const float4 w1 = *(const float4*)(wp + k + 4);
        const v8h xv = *(const v8h*)(xp + k);
        acc = fmaf(w0.x, (float)xv[0], acc); acc = fmaf(w0.y, (float)xv[1], acc);
        acc = fmaf(w0.z, (float)xv[2], acc); acc = fmaf(w0.w, (float)xv[3], acc);
        acc = fmaf(w1.x, (float)xv[4], acc); acc = fmaf(w1.y, (float)xv[5], acc);
        acc = fmaf(w1.z, (float)xv[6], acc); acc = fmaf(w1.w, (float)xv[7], acc);
    }
    gpre[g] = acc;
    __syncthreads();

    if (g < 64) {
        const float i  = sigf(gpre[g]);
        const float gg = tanhfast(gpre[128 + g]);
        const float o  = sigf(gpre[192 + g]);
        hb[g] = o * tanhfast(i * gg);
    }
    __syncthreads();

    if (g < 64) {
        float p = fc_w[g] * hlast[(size_t)b * 64 + g] + fc_w[64 + g] * hb[g];
        #pragma unroll
        for (int off = 32; off > 0; off >>= 1) p += __shfl_down(p, off);
        if (g == 0) out[b] = p + fc_b[0];
    }
}

extern "C" void kernel_launch(void* const* d_in, const int* in_sizes, int n_in,
                              void* d_out, int out_size, void* d_ws, size_t ws_size,
                              hipStream_t stream)
{
    const float* x    = (const float*)d_in[0];
    const float* w_ih = (const float*)d_in[1];
    const float* w_hh = (const float*)d_in[2];
    const float* b_ih = (const float*)d_in[3];
    const float* b_hh = (const float*)d_in[4];
    const float* fc_w = (const float*)d_in[5];
    const float* fc_b = (const float*)d_in[6];
    float* out = (float*)d_out;

    const size_t seq_b   = (size_t)BB * TT * 128 * sizeof(half_t);  // 128 MiB
    const size_t w16_b   = (size_t)1024 * 192 * sizeof(half_t);     // 384 KiB
    const size_t hlast_b = (size_t)BB * 64 * sizeof(float);         // 128 KiB

    if (ws_size >= w16_b + hlast_b + 2 * seq_b) {
        half_t* w16   = (half_t*)d_ws;
        float*  hlast = (float*)((char*)d_ws + w16_b);
        half_t* x16   = (half_t*)((char*)d_ws + w16_b + hlast_b);
        half_t* out1  = (half_t*)((char*)d_ws + w16_b + hlast_b + seq_b);

        cvt_w<<<768, 256, 0, stream>>>(w_ih, w_hh, w16);
        cvt_x<<<(BB * TT * 128 / 8) / 256, 256, 0, stream>>>(x, x16);
        lstm_scan<2, false, true, true, false><<<dim3(BB / 2, 2), 256, 0, stream>>>(
            x16, w16, w_ih, w_hh, b_ih, b_hh, 0, 1, out1, nullptr);
        lstm_scan<1, false, true, false, true><<<dim3(BB, 1), 256, 0, stream>>>(
            out1, w16, w_ih, w_hh, b_ih, b_hh, 1, 0, nullptr, hlast);
        l2bwd_fc<<<BB, 256, 0, stream>>>(out1, w_ih, b_ih, b_hh, hlast, fc_w, fc_b, out);
    } else if (ws_size >= 2 * seq_b + hlast_b) {
        half_t* x16   = (half_t*)d_ws;
        half_t* out1  = (half_t*)((char*)d_ws + seq_b);
        float*  hlast = (float*)((char*)d_ws + 2 * seq_b);

        cvt_x<<<(BB * TT * 128 / 8) / 256, 256, 0, stream>>>(x, x16);
        lstm_scan<2, false, false, true, false><<<dim3(BB / 2, 2), 256, 0, stream>>>(
            x16, nullptr, w_ih, w_hh, b_ih, b_hh, 0, 1, out1, nullptr);
        lstm_scan<1, false, false, false, true><<<dim3(BB, 1), 256, 0, stream>>>(
            out1, nullptr, w_ih, w_hh, b_ih, b_hh, 1, 0, nullptr, hlast);
        l2bwd_fc<<<BB, 256, 0, stream>>>(out1, w_ih, b_ih, b_hh, hlast, fc_w, fc_b, out);
    } else {
        half_t* out1  = (half_t*)d_ws;
        float*  hlast = (float*)((char*)d_ws + seq_b);

        lstm_scan<2, true, false, true, false><<<dim3(BB / 2, 2), 256, 0, stream>>>(
            x, nullptr, w_ih, w_hh, b_ih, b_hh, 0, 1, out1, nullptr);
        lstm_scan<1, false, false, false, true><<<dim3(BB, 1), 256, 0, stream>>>(
            out1, nullptr, w_ih, w_hh, b_ih, b_hh, 1, 0, nullptr, hlast);
        l2bwd_fc<<<BB, 256, 0, stream>>>(out1, w_ih, b_ih, b_hh, hlast, fc_w, fc_b, out);
    }
}

// Round 5
// 1612.155 us; speedup vs baseline: 1.2843x; 1.2843x over previous
//
#include <hip/hip_runtime.h>
#include <hip/hip_bf16.h>

#define TT 1024
#define BB 512

typedef _Float16 half_t;
typedef __attribute__((ext_vector_type(8))) _Float16 v8h;
typedef __attribute__((ext_vector_type(4))) float v4f;

// Single-instruction v_rcp_f32 (~1 ulp) — avoids the IEEE div sequence
// (div_scale/div_fmas/div_fixup ~8 instr) the compiler emits for '/'.
__device__ __forceinline__ float sigf(float x) {
    return __builtin_amdgcn_rcpf(1.0f + __expf(-x));
}
__device__ __forceinline__ float tanhfast(float x) {
    return fmaf(2.0f, __builtin_amdgcn_rcpf(1.0f + __expf(-2.0f * x)), -1.0f);
}

// Drain ONLY lgkmcnt (LDS) at the barrier — global prefetch stays in flight.
__device__ __forceinline__ void barrier_lds_only() {
    asm volatile("s_waitcnt lgkmcnt(0)\n\ts_barrier" ::: "memory");
}

// LSTM scan. Batch row r -> MFMA A/C row 4r: cell state for row r lives on
// lane group q==r, C-reg 0, so the nonlinearity executes once per step.
// 256 threads = 4 waves; wave wv owns gate columns {gt*64 + wv*16 + n16}.
// h double-buffered in LDS (rows padded to 72 halfs). One lds-only barrier
// per step. x prefetched 3 steps deep in registers (4 rotating buffers).
template<int R, bool IN_F32, bool W16, bool WRITE_SEQ, bool WRITE_LAST>
__global__ __launch_bounds__(256, 2)
void lstm_scan(const void* __restrict__ in_v, const half_t* __restrict__ w16,
               const float* __restrict__ w_ih, const float* __restrict__ w_hh,
               const float* __restrict__ b_ih, const float* __restrict__ b_hh,
               int layer, int use_grid_dir,
               half_t* __restrict__ out_seq, float* __restrict__ out_last)
{
    const int dir = use_grid_dir ? blockIdx.y : 0;
    const int wrow = layer * 2 + dir;
    const int col_off = dir * 64;
    const int b0 = blockIdx.x * R;
    const int wv = threadIdx.x >> 6;
    const int l  = threadIdx.x & 63;
    const int q  = l >> 4;
    const int n16 = l & 15;
    const int j = wv * 16 + n16;
    const int rowc = ((n16 >> 2) < R) ? (n16 >> 2) : (R - 1);  // clamped A-row->batch row

    __shared__ __align__(16) half_t hs[2][16][72];
    {
        v8h z;
        #pragma unroll
        for (int e = 0; e < 8; ++e) z[e] = (half_t)0.f;
        ((v8h*)hs)[threadIdx.x] = z;
        if (threadIdx.x < 32) ((v8h*)hs)[256 + threadIdx.x] = z;
    }

    // weight B-fragments: B[k][n16] = W[gt*64+j][k], k = kt*32+q*8+e
    v8h wb[4][6];
    float bias[4];
    #pragma unroll
    for (int gt = 0; gt < 4; ++gt) {
        const int grow = wrow * 256 + gt * 64 + j;
        if constexpr (W16) {
            const half_t* p = w16 + (size_t)grow * 192 + q * 8;
            #pragma unroll
            for (int kt = 0; kt < 6; ++kt) wb[gt][kt] = *(const v8h*)(p + kt * 32);
        } else {
            const float* pih = w_ih + (size_t)grow * 128 + q * 8;
            #pragma unroll
            for (int kt = 0; kt < 4; ++kt) {
                const float4 a = *(const float4*)(pih + kt * 32);
                const float4 b = *(const float4*)(pih + kt * 32 + 4);
                v8h f;
                f[0] = (half_t)a.x; f[1] = (half_t)a.y; f[2] = (half_t)a.z; f[3] = (half_t)a.w;
                f[4] = (half_t)b.x; f[5] = (half_t)b.y; f[6] = (half_t)b.z; f[7] = (half_t)b.w;
                wb[gt][kt] = f;
            }
            const float* phh = w_hh + (size_t)grow * 64 + q * 8;
            #pragma unroll
            for (int kt = 0; kt < 2; ++kt) {
                const float4 a = *(const float4*)(phh + kt * 32);
                const float4 b = *(const float4*)(phh + kt * 32 + 4);
                v8h f;
                f[0] = (half_t)a.x; f[1] = (half_t)a.y; f[2] = (half_t)a.z; f[3] = (half_t)a.w;
                f[4] = (half_t)b.x; f[5] = (half_t)b.y; f[6] = (half_t)b.z; f[7] = (half_t)b.w;
                wb[gt][4 + kt] = f;
            }
        }
        bias[gt] = b_ih[grow] + b_hh[grow];
    }

    const long t0 = dir ? (TT - 1) : 0;
    const long xstep = dir ? -128 : 128;

    const float*  xp32 = nullptr;
    const half_t* xp16 = nullptr;
    if constexpr (IN_F32) xp32 = (const float*)in_v + ((size_t)(b0 + rowc) * TT + t0) * 128 + q * 8;
    else                  xp16 = (const half_t*)in_v + ((size_t)(b0 + rowc) * TT + t0) * 128 + q * 8;

    half_t* op = nullptr;
    if constexpr (WRITE_SEQ) {
        const int qr = (q < R) ? q : (R - 1);
        op = out_seq + ((size_t)(b0 + qr) * TT + t0) * 128 + col_off + j;
    }

    auto load_x = [&](v8h* dst) {
        if constexpr (IN_F32) {
            #pragma unroll
            for (int kt = 0; kt < 4; ++kt) {
                const float4 a = *(const float4*)(xp32 + kt * 32);
                const float4 b = *(const float4*)(xp32 + kt * 32 + 4);
                v8h f;
                f[0] = (half_t)a.x; f[1] = (half_t)a.y; f[2] = (half_t)a.z; f[3] = (half_t)a.w;
                f[4] = (half_t)b.x; f[5] = (half_t)b.y; f[6] = (half_t)b.z; f[7] = (half_t)b.w;
                dst[kt] = f;
            }
        } else {
            #pragma unroll
            for (int kt = 0; kt < 4; ++kt) dst[kt] = *(const v8h*)(xp16 + kt * 32);
        }
    };
    auto adv_x = [&]() { if constexpr (IN_F32) xp32 += xstep; else xp16 += xstep; };

    float c = 0.f, hcur = 0.f;
    const v4f z4 = {0.f, 0.f, 0.f, 0.f};

    auto step = [&](const v8h (&xf)[4], int pb) {
        const v8h hf0 = *(const v8h*)&hs[pb][n16][q * 8];
        const v8h hf1 = *(const v8h*)&hs[pb][n16][32 + q * 8];
        v4f acc[4];
        #pragma unroll
        for (int gt = 0; gt < 4; ++gt) {
            v4f a;
            a = __builtin_amdgcn_mfma_f32_16x16x32_f16(xf[0], wb[gt][0], z4, 0, 0, 0);
            a = __builtin_amdgcn_mfma_f32_16x16x32_f16(xf[1], wb[gt][1], a, 0, 0, 0);
            a = __builtin_amdgcn_mfma_f32_16x16x32_f16(xf[2], wb[gt][2], a, 0, 0, 0);
            a = __builtin_amdgcn_mfma_f32_16x16x32_f16(xf[3], wb[gt][3], a, 0, 0, 0);
            a = __builtin_amdgcn_mfma_f32_16x16x32_f16(hf0,   wb[gt][4], a, 0, 0, 0);
            a = __builtin_amdgcn_mfma_f32_16x16x32_f16(hf1,   wb[gt][5], a, 0, 0, 0);
            acc[gt] = a;
        }
        const float iv = sigf(acc[0][0] + bias[0]);
        const float fv = sigf(acc[1][0] + bias[1]);
        const float gv = tanhfast(acc[2][0] + bias[2]);
        const float ov = sigf(acc[3][0] + bias[3]);
        c = fv * c + iv * gv;
        const float h = ov * tanhfast(c);
        if (q < R) {
            const half_t h16 = (half_t)h;
            hs[pb ^ 1][4 * q][j] = h16;
            if constexpr (WRITE_SEQ) { *op = h16; op += xstep; }
            hcur = h;
        }
    };

    // depth-3 prefetch: 4 rotating register buffers
    v8h x0[4], x1[4], x2[4], x3[4];
    load_x(x0); adv_x();
    load_x(x1); adv_x();
    load_x(x2); adv_x();
    barrier_lds_only();  // hs zero-init visible

    for (int tt = 0; tt < TT; tt += 4) {
        if (tt + 3 < TT) { load_x(x3); adv_x(); }
        step(x0, 0); barrier_lds_only();
        if (tt + 4 < TT) { load_x(x0); adv_x(); }
        step(x1, 1); barrier_lds_only();
        if (tt + 5 < TT) { load_x(x1); adv_x(); }
        step(x2, 0); barrier_lds_only();
        if (tt + 6 < TT) { load_x(x2); adv_x(); }
        step(x3, 1); barrier_lds_only();
    }

    if constexpr (WRITE_LAST) {
        if (q < R) out_last[(size_t)(b0 + q) * 64 + j] = hcur;
    }
}

// ---------------- weight fp32 -> packed fp16 rows of 192 ----------------
__global__ __launch_bounds__(256)
void cvt_w(const float* __restrict__ w_ih, const float* __restrict__ w_hh,
           half_t* __restrict__ w16)
{
    const int id = blockIdx.x * 256 + threadIdx.x;  // 1024 rows * 192
    const int row = id / 192, k = id % 192;
    const float v = (k < 128) ? w_ih[row * 128 + k] : w_hh[row * 64 + (k - 128)];
    w16[id] = (half_t)v;
}

// ---------------- x fp32 -> fp16 ----------------
__global__ __launch_bounds__(256)
void cvt_x(const float* __restrict__ in, half_t* __restrict__ out)
{
    const size_t i = ((size_t)blockIdx.x * 256 + threadIdx.x) * 8;
    const float4 a = *(const float4*)(in + i);
    const float4 b = *(const float4*)(in + i + 4);
    v8h f;
    f[0] = (half_t)a.x; f[1] = (half_t)a.y; f[2] = (half_t)a.z; f[3] = (half_t)a.w;
    f[4] = (half_t)b.x; f[5] = (half_t)b.y; f[6] = (half_t)b.z; f[7] = (half_t)b.w;
    *(v8h*)(out + i) = f;
}

// ---------------- Layer 2 backward (single step, h0=0) + FC ----------------
__global__ __launch_bounds__(256)
void l2bwd_fc(const half_t* __restrict__ in, const float* __restrict__ w_ih,
              const float* __restrict__ b_ih, const float* __restrict__ b_hh,
              const float* __restrict__ hlast, const float* __restrict__ fc_w,
              const float* __restrict__ fc_b, float* __restrict__ out)
{
    const int b = blockIdx.x;
    const int g = threadIdx.x;
    __shared__ float gpre[256];
    __shared__ float hb[64];

    float acc = b_ih[3 * 256 + g] + b_hh[3 * 256 + g];
    const float* wp = w_ih + ((size_t)(3 * 256 + g)) * 128;
    const half_t* xp = in + ((size_t)b * TT + (TT - 1)) * 128;
    #pragma unroll
    for (int k = 0; k < 128; k += 8) {
        const float4 w0 = *(const float4*)(wp + k);
        const float4 w1 = *(const float4*)(wp + k + 4);
        const v8h xv = *(const v8h*)(xp + k);
        acc = fmaf(w0.x, (float)xv[0], acc); acc = fmaf(w0.y, (float)xv[1], acc);
        acc = fmaf(w0.z, (float)xv[2], acc); acc = fmaf(w0.w, (float)xv[3], acc);
        acc = fmaf(w1.x, (float)xv[4], acc); acc = fmaf(w1.y, (float)xv[5], acc);
        acc = fmaf(w1.z, (float)xv[6], acc); acc = fmaf(w1.w, (float)xv[7], acc);
    }
    gpre[g] = acc;
    __syncthreads();

    if (g < 64) {
        const float i  = sigf(gpre[g]);
        const float gg = tanhfast(gpre[128 + g]);
        const float o  = sigf(gpre[192 + g]);
        hb[g] = o * tanhfast(i * gg);
    }
    __syncthreads();

    if (g < 64) {
        float p = fc_w[g] * hlast[(size_t)b * 64 + g] + fc_w[64 + g] * hb[g];
        #pragma unroll
        for (int off = 32; off > 0; off >>= 1) p += __shfl_down(p, off);
        if (g == 0) out[b] = p + fc_b[0];
    }
}

extern "C" void kernel_launch(void* const* d_in, const int* in_sizes, int n_in,
                              void* d_out, int out_size, void* d_ws, size_t ws_size,
                              hipStream_t stream)
{
    const float* x    = (const float*)d_in[0];
    const float* w_ih = (const float*)d_in[1];
    const float* w_hh = (const float*)d_in[2];
    const float* b_ih = (const float*)d_in[3];
    const float* b_hh = (const float*)d_in[4];
    const float* fc_w = (const float*)d_in[5];
    const float* fc_b = (const float*)d_in[6];
    float* out = (float*)d_out;

    const size_t seq_b   = (size_t)BB * TT * 128 * sizeof(half_t);  // 128 MiB
    const size_t w16_b   = (size_t)1024 * 192 * sizeof(half_t);     // 384 KiB
    const size_t hlast_b = (size_t)BB * 64 * sizeof(float);         // 128 KiB

    if (ws_size >= w16_b + hlast_b + 2 * seq_b) {
        half_t* w16   = (half_t*)d_ws;
        float*  hlast = (float*)((char*)d_ws + w16_b);
        half_t* x16   = (half_t*)((char*)d_ws + w16_b + hlast_b);
        half_t* out1  = (half_t*)((char*)d_ws + w16_b + hlast_b + seq_b);

        cvt_w<<<768, 256, 0, stream>>>(w_ih, w_hh, w16);
        cvt_x<<<(BB * TT * 128 / 8) / 256, 256, 0, stream>>>(x, x16);
        lstm_scan<2, false, true, true, false><<<dim3(BB / 2, 2), 256, 0, stream>>>(
            x16, w16, w_ih, w_hh, b_ih, b_hh, 0, 1, out1, nullptr);
        lstm_scan<1, false, true, false, true><<<dim3(BB, 1), 256, 0, stream>>>(
            out1, w16, w_ih, w_hh, b_ih, b_hh, 1, 0, nullptr, hlast);
        l2bwd_fc<<<BB, 256, 0, stream>>>(out1, w_ih, b_ih, b_hh, hlast, fc_w, fc_b, out);
    } else if (ws_size >= 2 * seq_b + hlast_b) {
        half_t* x16   = (half_t*)d_ws;
        half_t* out1  = (half_t*)((char*)d_ws + seq_b);
        float*  hlast = (float*)((char*)d_ws + 2 * seq_b);

        cvt_x<<<(BB * TT * 128 / 8) / 256, 256, 0, stream>>>(x, x16);
        lstm_scan<2, false, false, true, false><<<dim3(BB / 2, 2), 256, 0, stream>>>(
            x16, nullptr, w_ih, w_hh, b_ih, b_hh, 0, 1, out1, nullptr);
        lstm_scan<1, false, false, false, true><<<dim3(BB, 1), 256, 0, stream>>>(
            out1, nullptr, w_ih, w_hh, b_ih, b_hh, 1, 0, nullptr, hlast);
        l2bwd_fc<<<BB, 256, 0, stream>>>(out1, w_ih, b_ih, b_hh, hlast, fc_w, fc_b, out);
    } else {
        half_t* out1  = (half_t*)d_ws;
        float*  hlast = (float*)((char*)d_ws + seq_b);

        lstm_scan<2, true, false, true, false><<<dim3(BB / 2, 2), 256, 0, stream>>>(
            x, nullptr, w_ih, w_hh, b_ih, b_hh, 0, 1, out1, nullptr);
        lstm_scan<1, false, false, false, true><<<dim3(BB, 1), 256, 0, stream>>>(
            out1, nullptr, w_ih, w_hh, b_ih, b_hh, 1, 0, nullptr, hlast);
        l2bwd_fc<<<BB, 256, 0, stream>>>(out1, w_ih, b_ih, b_hh, hlast, fc_w, fc_b, out);
    }
}

// Round 6
// 1305.840 us; speedup vs baseline: 1.5855x; 1.2346x over previous
//
#include <hip/hip_runtime.h>
#include <hip/hip_bf16.h>

#define TT 1024
#define BB 512

typedef _Float16 half_t;
typedef __attribute__((ext_vector_type(8))) _Float16 v8h;
typedef __attribute__((ext_vector_type(4))) float v4f;

// Single-instruction v_rcp_f32 — avoids the IEEE div sequence.
__device__ __forceinline__ float sigf(float x) {
    return __builtin_amdgcn_rcpf(1.0f + __expf(-x));
}
__device__ __forceinline__ float tanhfast(float x) {
    return fmaf(2.0f, __builtin_amdgcn_rcpf(1.0f + __expf(-2.0f * x)), -1.0f);
}

// Drain ONLY lgkmcnt (LDS) at the barrier — global prefetch stays in flight.
__device__ __forceinline__ void barrier_lds_only() {
    asm volatile("s_waitcnt lgkmcnt(0)\n\ts_barrier" ::: "memory");
}

// LSTM scan, 1 block per CU (grid == #blocks <= 256, launch_bounds min-waves 1):
// the scan wall is pure per-SIMD issue; co-resident blocks serialize on the
// SIMD issue port (R5 counters: wall == 2x per-wave issue at 2 blocks/CU).
// R=4 batch rows/block: row r -> MFMA A/C row 4r; cell state for row r lives
// on lane group q==r, C-reg 0 -> all 64 lanes run the nonlinearity once,
// lane (q,j) owns (row q, hidden j) for its wave's 16 columns.
// Per-gate MFMA chain split in two 3-deep halves (1 wave/SIMD can't hide a
// 6-deep dependent chain). h double-buffered in LDS (rows padded to 72).
template<int R, bool IN_F32, bool W16, bool WRITE_SEQ, bool WRITE_LAST>
__global__ __launch_bounds__(256, 1)
void lstm_scan(const void* __restrict__ in_v, const half_t* __restrict__ w16,
               const float* __restrict__ w_ih, const float* __restrict__ w_hh,
               const float* __restrict__ b_ih, const float* __restrict__ b_hh,
               int layer, int use_grid_dir,
               half_t* __restrict__ out_seq, float* __restrict__ out_last)
{
    const int dir = use_grid_dir ? blockIdx.y : 0;
    const int wrow = layer * 2 + dir;
    const int col_off = dir * 64;
    const int b0 = blockIdx.x * R;
    const int wv = threadIdx.x >> 6;
    const int l  = threadIdx.x & 63;
    const int q  = l >> 4;
    const int n16 = l & 15;
    const int j = wv * 16 + n16;
    const int rowc = ((n16 >> 2) < R) ? (n16 >> 2) : (R - 1);  // A-row -> batch row (clamped)

    __shared__ __align__(16) half_t hs[2][16][72];
    {
        v8h z;
        #pragma unroll
        for (int e = 0; e < 8; ++e) z[e] = (half_t)0.f;
        ((v8h*)hs)[threadIdx.x] = z;
        if (threadIdx.x < 32) ((v8h*)hs)[256 + threadIdx.x] = z;
    }

    // weight B-fragments: B[k][n16] = W[gt*64+j][k], k = kt*32+q*8+e
    v8h wb[4][6];
    float bias[4];
    #pragma unroll
    for (int gt = 0; gt < 4; ++gt) {
        const int grow = wrow * 256 + gt * 64 + j;
        if constexpr (W16) {
            const half_t* p = w16 + (size_t)grow * 192 + q * 8;
            #pragma unroll
            for (int kt = 0; kt < 6; ++kt) wb[gt][kt] = *(const v8h*)(p + kt * 32);
        } else {
            const float* pih = w_ih + (size_t)grow * 128 + q * 8;
            #pragma unroll
            for (int kt = 0; kt < 4; ++kt) {
                const float4 a = *(const float4*)(pih + kt * 32);
                const float4 b = *(const float4*)(pih + kt * 32 + 4);
                v8h f;
                f[0] = (half_t)a.x; f[1] = (half_t)a.y; f[2] = (half_t)a.z; f[3] = (half_t)a.w;
                f[4] = (half_t)b.x; f[5] = (half_t)b.y; f[6] = (half_t)b.z; f[7] = (half_t)b.w;
                wb[gt][kt] = f;
            }
            const float* phh = w_hh + (size_t)grow * 64 + q * 8;
            #pragma unroll
            for (int kt = 0; kt < 2; ++kt) {
                const float4 a = *(const float4*)(phh + kt * 32);
                const float4 b = *(const float4*)(phh + kt * 32 + 4);
                v8h f;
                f[0] = (half_t)a.x; f[1] = (half_t)a.y; f[2] = (half_t)a.z; f[3] = (half_t)a.w;
                f[4] = (half_t)b.x; f[5] = (half_t)b.y; f[6] = (half_t)b.z; f[7] = (half_t)b.w;
                wb[gt][4 + kt] = f;
            }
        }
        bias[gt] = b_ih[grow] + b_hh[grow];
    }

    const long t0 = dir ? (TT - 1) : 0;
    const long xstep = dir ? -128 : 128;

    const float*  xp32 = nullptr;
    const half_t* xp16 = nullptr;
    if constexpr (IN_F32) xp32 = (const float*)in_v + ((size_t)(b0 + rowc) * TT + t0) * 128 + q * 8;
    else                  xp16 = (const half_t*)in_v + ((size_t)(b0 + rowc) * TT + t0) * 128 + q * 8;

    half_t* op = nullptr;
    if constexpr (WRITE_SEQ) {
        const int qr = (q < R) ? q : (R - 1);
        op = out_seq + ((size_t)(b0 + qr) * TT + t0) * 128 + col_off + j;
    }

    auto load_x = [&](v8h* dst) {
        if constexpr (IN_F32) {
            #pragma unroll
            for (int kt = 0; kt < 4; ++kt) {
                const float4 a = *(const float4*)(xp32 + kt * 32);
                const float4 b = *(const float4*)(xp32 + kt * 32 + 4);
                v8h f;
                f[0] = (half_t)a.x; f[1] = (half_t)a.y; f[2] = (half_t)a.z; f[3] = (half_t)a.w;
                f[4] = (half_t)b.x; f[5] = (half_t)b.y; f[6] = (half_t)b.z; f[7] = (half_t)b.w;
                dst[kt] = f;
            }
        } else {
            #pragma unroll
            for (int kt = 0; kt < 4; ++kt) dst[kt] = *(const v8h*)(xp16 + kt * 32);
        }
    };
    auto adv_x = [&]() { if constexpr (IN_F32) xp32 += xstep; else xp16 += xstep; };

    float c = 0.f, hcur = 0.f;
    const v4f z4 = {0.f, 0.f, 0.f, 0.f};

    auto step = [&](const v8h (&xf)[4], int pb) {
        const v8h hf0 = *(const v8h*)&hs[pb][n16][q * 8];
        const v8h hf1 = *(const v8h*)&hs[pb][n16][32 + q * 8];
        float pre[4];
        #pragma unroll
        for (int gt = 0; gt < 4; ++gt) {
            // two 3-deep chains instead of one 6-deep (latency at 1 wave/SIMD)
            v4f a = __builtin_amdgcn_mfma_f32_16x16x32_f16(xf[0], wb[gt][0], z4, 0, 0, 0);
            a = __builtin_amdgcn_mfma_f32_16x16x32_f16(xf[1], wb[gt][1], a, 0, 0, 0);
            a = __builtin_amdgcn_mfma_f32_16x16x32_f16(hf0,   wb[gt][4], a, 0, 0, 0);
            v4f b = __builtin_amdgcn_mfma_f32_16x16x32_f16(xf[2], wb[gt][2], z4, 0, 0, 0);
            b = __builtin_amdgcn_mfma_f32_16x16x32_f16(xf[3], wb[gt][3], b, 0, 0, 0);
            b = __builtin_amdgcn_mfma_f32_16x16x32_f16(hf1,   wb[gt][5], b, 0, 0, 0);
            pre[gt] = a[0] + b[0] + bias[gt];
        }
        const float iv = sigf(pre[0]);
        const float fv = sigf(pre[1]);
        const float gv = tanhfast(pre[2]);
        const float ov = sigf(pre[3]);
        c = fv * c + iv * gv;
        const float h = ov * tanhfast(c);
        if (q < R) {
            const half_t h16 = (half_t)h;
            hs[pb ^ 1][4 * q][j] = h16;
            if constexpr (WRITE_SEQ) { *op = h16; op += xstep; }
            hcur = h;
        }
    };

    // depth-3 register prefetch: 4 rotating buffers
    v8h x0[4], x1[4], x2[4], x3[4];
    load_x(x0); adv_x();
    load_x(x1); adv_x();
    load_x(x2); adv_x();
    barrier_lds_only();  // hs zero-init visible

    for (int tt = 0; tt < TT; tt += 4) {
        if (tt + 3 < TT) { load_x(x3); adv_x(); }
        step(x0, 0); barrier_lds_only();
        if (tt + 4 < TT) { load_x(x0); adv_x(); }
        step(x1, 1); barrier_lds_only();
        if (tt + 5 < TT) { load_x(x1); adv_x(); }
        step(x2, 0); barrier_lds_only();
        if (tt + 6 < TT) { load_x(x2); adv_x(); }
        step(x3, 1); barrier_lds_only();
    }

    if constexpr (WRITE_LAST) {
        if (q < R) out_last[(size_t)(b0 + q) * 64 + j] = hcur;
    }
}

// ---------------- weight fp32 -> packed fp16 rows of 192 ----------------
__global__ __launch_bounds__(256)
void cvt_w(const float* __restrict__ w_ih, const float* __restrict__ w_hh,
           half_t* __restrict__ w16)
{
    const int id = blockIdx.x * 256 + threadIdx.x;  // 1024 rows * 192
    const int row = id / 192, k = id % 192;
    const float v = (k < 128) ? w_ih[row * 128 + k] : w_hh[row * 64 + (k - 128)];
    w16[id] = (half_t)v;
}

// ---------------- x fp32 -> fp16 ----------------
__global__ __launch_bounds__(256)
void cvt_x(const float* __restrict__ in, half_t* __restrict__ out)
{
    const size_t i = ((size_t)blockIdx.x * 256 + threadIdx.x) * 8;
    const float4 a = *(const float4*)(in + i);
    const float4 b = *(const float4*)(in + i + 4);
    v8h f;
    f[0] = (half_t)a.x; f[1] = (half_t)a.y; f[2] = (half_t)a.z; f[3] = (half_t)a.w;
    f[4] = (half_t)b.x; f[5] = (half_t)b.y; f[6] = (half_t)b.z; f[7] = (half_t)b.w;
    *(v8h*)(out + i) = f;
}

// ---------------- Layer 2 backward (single step, h0=0) + FC ----------------
__global__ __launch_bounds__(256)
void l2bwd_fc(const half_t* __restrict__ in, const float* __restrict__ w_ih,
              const float* __restrict__ b_ih, const float* __restrict__ b_hh,
              const float* __restrict__ hlast, const float* __restrict__ fc_w,
              const float* __restrict__ fc_b, float* __restrict__ out)
{
    const int b = blockIdx.x;
    const int g = threadIdx.x;
    __shared__ float gpre[256];
    __shared__ float hb[64];

    float acc = b_ih[3 * 256 + g] + b_hh[3 * 256 + g];
    const float* wp = w_ih + ((size_t)(3 * 256 + g)) * 128;
    const half_t* xp = in + ((size_t)b * TT + (TT - 1)) * 128;
    #pragma unroll
    for (int k = 0; k < 128; k += 8) {
        const float4 w0 = *(const float4*)(wp + k);
        const float4 w1 = *(const float4*)(wp + k + 4);
        const v8h xv = *(const v8h*)(xp + k);
        acc = fmaf(w0.x, (float)xv[0], acc); acc = fmaf(w0.y, (float)xv[1], acc);
        acc = fmaf(w0.z, (float)xv[2], acc); acc = fmaf(w0.w, (float)xv[3], acc);
        acc = fmaf(w1.x, (float)xv[4], acc); acc = fmaf(w1.y, (float)xv[5], acc);
        acc = fmaf(w1.z, (float)xv[6], acc); acc = fmaf(w1.w, (float)xv[7], acc);
    }
    gpre[g] = acc;
    __syncthreads();

    if (g < 64) {
        const float i  = sigf(gpre[g]);
        const float gg = tanhfast(gpre[128 + g]);
        const float o  = sigf(gpre[192 + g]);
        hb[g] = o * tanhfast(i * gg);
    }
    __syncthreads();

    if (g < 64) {
        float p = fc_w[g] * hlast[(size_t)b * 64 + g] + fc_w[64 + g] * hb[g];
        #pragma unroll
        for (int off = 32; off > 0; off >>= 1) p += __shfl_down(p, off);
        if (g == 0) out[b] = p + fc_b[0];
    }
}

extern "C" void kernel_launch(void* const* d_in, const int* in_sizes, int n_in,
                              void* d_out, int out_size, void* d_ws, size_t ws_size,
                              hipStream_t stream)
{
    const float* x    = (const float*)d_in[0];
    const float* w_ih = (const float*)d_in[1];
    const float* w_hh = (const float*)d_in[2];
    const float* b_ih = (const float*)d_in[3];
    const float* b_hh = (const float*)d_in[4];
    const float* fc_w = (const float*)d_in[5];
    const float* fc_b = (const float*)d_in[6];
    float* out = (float*)d_out;

    const size_t seq_b   = (size_t)BB * TT * 128 * sizeof(half_t);  // 128 MiB
    const size_t w16_b   = (size_t)1024 * 192 * sizeof(half_t);     // 384 KiB
    const size_t hlast_b = (size_t)BB * 64 * sizeof(float);         // 128 KiB

    if (ws_size >= w16_b + hlast_b + 2 * seq_b) {
        half_t* w16   = (half_t*)d_ws;
        float*  hlast = (float*)((char*)d_ws + w16_b);
        half_t* x16   = (half_t*)((char*)d_ws + w16_b + hlast_b);
        half_t* out1  = (half_t*)((char*)d_ws + w16_b + hlast_b + seq_b);

        cvt_w<<<768, 256, 0, stream>>>(w_ih, w_hh, w16);
        cvt_x<<<(BB * TT * 128 / 8) / 256, 256, 0, stream>>>(x, x16);
        lstm_scan<4, false, true, true, false><<<dim3(BB / 4, 2), 256, 0, stream>>>(
            x16, w16, w_ih, w_hh, b_ih, b_hh, 0, 1, out1, nullptr);
        lstm_scan<4, false, true, false, true><<<dim3(BB / 4, 1), 256, 0, stream>>>(
            out1, w16, w_ih, w_hh, b_ih, b_hh, 1, 0, nullptr, hlast);
        l2bwd_fc<<<BB, 256, 0, stream>>>(out1, w_ih, b_ih, b_hh, hlast, fc_w, fc_b, out);
    } else if (ws_size >= 2 * seq_b + hlast_b) {
        half_t* x16   = (half_t*)d_ws;
        half_t* out1  = (half_t*)((char*)d_ws + seq_b);
        float*  hlast = (float*)((char*)d_ws + 2 * seq_b);

        cvt_x<<<(BB * TT * 128 / 8) / 256, 256, 0, stream>>>(x, x16);
        lstm_scan<4, false, false, true, false><<<dim3(BB / 4, 2), 256, 0, stream>>>(
            x16, nullptr, w_ih, w_hh, b_ih, b_hh, 0, 1, out1, nullptr);
        lstm_scan<4, false, false, false, true><<<dim3(BB / 4, 1), 256, 0, stream>>>(
            out1, nullptr, w_ih, w_hh, b_ih, b_hh, 1, 0, nullptr, hlast);
        l2bwd_fc<<<BB, 256, 0, stream>>>(out1, w_ih, b_ih, b_hh, hlast, fc_w, fc_b, out);
    } else {
        half_t* out1  = (half_t*)d_ws;
        float*  hlast = (float*)((char*)d_ws + seq_b);

        lstm_scan<4, true, false, true, false><<<dim3(BB / 4, 2), 256, 0, stream>>>(
            x, nullptr, w_ih, w_hh, b_ih, b_hh, 0, 1, out1, nullptr);
        lstm_scan<4, false, false, false, true><<<dim3(BB / 4, 1), 256, 0, stream>>>(
            out1, nullptr, w_ih, w_hh, b_ih, b_hh, 1, 0, nullptr, hlast);
        l2bwd_fc<<<BB, 256, 0, stream>>>(out1, w_ih, b_ih, b_hh, hlast, fc_w, fc_b, out);
    }
}